// Round 16
// baseline (261.796 us; speedup 1.0000x reference)
//
#include <hip/hip_runtime.h>

typedef __attribute__((ext_vector_type(8))) short short8_t;   // 8 bf16 (4 VGPRs)
typedef __attribute__((ext_vector_type(4))) float f32x4;      // 4 fp32

#define AS1 __attribute__((address_space(1)))
#define AS3 __attribute__((address_space(3)))

__device__ inline void gload_lds16(const void* g, void* l) {
  // async global->LDS, 16B per lane; LDS dest is wave-uniform base + lane*16
  __builtin_amdgcn_global_load_lds((AS1 void*)g, (AS3 void*)l, 16, 0, 0);
}

__device__ inline unsigned short f2bf(float f) {  // RNE f32->bf16
  unsigned int u = __builtin_bit_cast(unsigned int, f);
  u += 0x7fffu + ((u >> 16) & 1u);
  return (unsigned short)(u >> 16);
}
__device__ inline float bfu2f(unsigned short u) {
  return __builtin_bit_cast(float, ((unsigned int)u) << 16);
}
__device__ inline float sigmoidf_(float x) {
  x = fminf(fmaxf(x, -30.f), 30.f);
  return 1.f / (1.f + __expf(-x));
}
__device__ inline float tanhf_(float x) {
  x = fminf(fmaxf(x, -15.f), 15.f);
  float e = __expf(2.f * x);
  return (e - 1.f) / (e + 1.f);
}

// ---------------- pass 0: f32 -> bf16 conversion (all 4 arrays, 1 launch) ---
__global__ __launch_bounds__(256) void cvt_bf16_all(
    const float* __restrict__ x,  unsigned short* __restrict__ xb,
    const float* __restrict__ hx, unsigned short* __restrict__ hxb,
    const float* __restrict__ Wi, unsigned short* __restrict__ wib,
    const float* __restrict__ Wh, unsigned short* __restrict__ whb) {
  int blk = blockIdx.x;
  const float* src; unsigned short* dst;
  if (blk < 4096)       { src = x;  dst = xb; }
  else if (blk < 8192)  { src = hx; dst = hxb; blk -= 4096; }
  else if (blk < 10240) { src = Wi; dst = wib; blk -= 8192; }
  else                  { src = Wh; dst = whb; blk -= 10240; }
  int i = (blk * 256 + threadIdx.x) * 8;
  const float4* s = reinterpret_cast<const float4*>(src + i);
  float4 a = s[0], b = s[1];
  union { unsigned short us[8]; uint4 v; } o;
  o.us[0] = f2bf(a.x); o.us[1] = f2bf(a.y); o.us[2] = f2bf(a.z); o.us[3] = f2bf(a.w);
  o.us[4] = f2bf(b.x); o.us[5] = f2bf(b.y); o.us[6] = f2bf(b.z); o.us[7] = f2bf(b.w);
  *reinterpret_cast<uint4*>(dst + i) = o.v;
}

// ---------------- pass 1: dual GEMM — 128² tile, 3 blocks/CU, counted vmcnt
// C[m,n] = sum_k A[m,k]*B[n,k]. M=8192, N=4096, K=1024.
// BM=BN=128, BK=32, 256 thr = 4 waves (2M x 2N), wave tile 64x64, acc[4][4]
// (64 AGPR) + ~50 VGPR ≈ 114 unified regs -> not register-capped; LDS = 3
// rotating buffers x (8KB A + 8KB B) = 48KB -> 3 blocks/CU (12 waves/CU,
// 1.5x the 256² variant). Mechanism under test: INTER-BLOCK overlap — other
// blocks' MFMA covers this block's boundary drain (m97's 912 TF mechanism),
// on top of our 0-conflict swizzle + counted-vmcnt boundary (m97 had neither).
// Per K-tile: {stage kt+2 -> (kt+2)%3 (4 gloads); read 8 b128 from kt%3;
// lgkm0; setprio1; 16 MFMA; setprio0; vmcnt(4); barrier}.
// Hazards: stage target (kt+2)%3 == (kt-1)%3, whose reads retired before
// tile kt-1's boundary barrier (each wave's lgkm0 precedes its MFMA precedes
// the barrier) -> no mid-barrier needed. Boundary vmcnt(4): only kt+2's 4
// loads are younger than kt+1's -> kt+1 resident for all waves past barrier.
// Swizzle (PMC-verified 0-conflict at this exact BK=32 geometry, R11):
// write: linear idx = g*256+t, row=idx>>2, phys slot idx&3 holds logical
// (idx&3)^((idx>>3)&3); read: slot offset (fq^((fr>>1)&3))*8. Source
// pre-swizzled (rule #21). Accumulation K-ascending -> absmax 0.03125.
__global__ __launch_bounds__(256, 3) void gemm_dual(
    const unsigned short* __restrict__ Xb, const unsigned short* __restrict__ Hxb,
    const unsigned short* __restrict__ Wib, const unsigned short* __restrict__ Whb,
    unsigned short* __restrict__ Gi, unsigned short* __restrict__ Gh) {
  const int K = 1024, N = 4096, NT = 32;  // NT = K/32 K-tiles
  const unsigned short* A  = blockIdx.z ? Hxb : Xb;
  const unsigned short* Bw = blockIdx.z ? Whb : Wib;
  unsigned short* C        = blockIdx.z ? Gh : Gi;

  __shared__ __align__(16) unsigned short lA[3 * 128 * 32];  // 24 KB
  __shared__ __align__(16) unsigned short lB[3 * 128 * 32];  // 24 KB

  const int t    = threadIdx.x;        // 0..255
  const int wid  = t >> 6;             // 0..3
  const int lane = t & 63;
  const int fr = lane & 15, fq = lane >> 4;
  const int wm = wid >> 1;             // 0..1  (M-split)
  const int wn = wid & 1;              // 0..1  (N-split)
  const int m0 = blockIdx.y * 128, n0 = blockIdx.x * 128;

  // stage full K-tile kt (A and B, 8KB each) into rotation buffer sb
  auto stage = [&](int kt, int sb) {
    if (kt >= NT) return;
    const int k0 = kt * 32;
#pragma unroll
    for (int g = 0; g < 2; ++g) {
      int idx = g * 256 + t;
      int row = idx >> 2;
      int ls  = (idx & 3) ^ ((idx >> 3) & 3);
      gload_lds16(A  + (size_t)(m0 + row) * K + k0 + ls * 8,
                  lA + sb * 4096 + g * 2048 + wid * 512);
      gload_lds16(Bw + (size_t)(n0 + row) * K + k0 + ls * 8,
                  lB + sb * 4096 + g * 2048 + wid * 512);
    }
  };

  f32x4 acc[4][4];
#pragma unroll
  for (int i = 0; i < 4; ++i)
#pragma unroll
    for (int j = 0; j < 4; ++j) acc[i][j] = (f32x4){0.f, 0.f, 0.f, 0.f};

  // prologue: tiles 0 and 1 in flight; wait tile 0 (tile 1's 4 outstanding)
  stage(0, 0);
  stage(1, 1);
  asm volatile("s_waitcnt vmcnt(4)");
  __builtin_amdgcn_s_barrier();

  // read-side swizzle: 16B slot element offset = (fq ^ ((fr>>1)&3)) * 8
  const int swz = (fq ^ ((fr >> 1) & 3)) * 8;

  short8_t av[4], bv[4];

  int rb = 0;                          // read buffer = kt % 3
  for (int kt = 0; kt < NT; ++kt) {
    int sb = rb + 2; if (sb >= 3) sb -= 3;   // stage buffer = (kt+2) % 3
    stage(kt + 2, sb);

    const unsigned short* As = lA + rb * 4096;
    const unsigned short* Bs = lB + rb * 4096;
#pragma unroll
    for (int m = 0; m < 4; ++m)
      av[m] = *reinterpret_cast<const short8_t*>(As + (wm * 64 + m * 16 + fr) * 32 + swz);
#pragma unroll
    for (int n = 0; n < 4; ++n)
      bv[n] = *reinterpret_cast<const short8_t*>(Bs + (wn * 64 + n * 16 + fr) * 32 + swz);

    asm volatile("s_waitcnt lgkmcnt(0)");
    __builtin_amdgcn_s_setprio(1);
#pragma unroll
    for (int m = 0; m < 4; ++m)
#pragma unroll
      for (int n = 0; n < 4; ++n)
        acc[m][n] = __builtin_amdgcn_mfma_f32_16x16x32_bf16(av[m], bv[n], acc[m][n], 0, 0, 0);
    __builtin_amdgcn_s_setprio(0);

    // boundary: tile kt+1 resident past this barrier (only kt+2's 4 younger)
    if (kt + 2 < NT) {
      asm volatile("s_waitcnt vmcnt(4)");
    } else if (kt + 1 < NT) {
      asm volatile("s_waitcnt vmcnt(0)");
    }
    __builtin_amdgcn_s_barrier();
    rb = (rb + 1 == 3) ? 0 : rb + 1;
  }

  // epilogue: D row = fq*4 + r, col = fr (m89-verified layout)
#pragma unroll
  for (int m = 0; m < 4; ++m)
#pragma unroll
    for (int n = 0; n < 4; ++n)
#pragma unroll
      for (int r = 0; r < 4; ++r) {
        int row = m0 + wm * 64 + m * 16 + fq * 4 + r;
        int col = n0 + wn * 64 + n * 16 + fr;
        C[(size_t)row * N + col] = f2bf(acc[m][n][r]);
      }
}

// ---------------- pass 2: fused LN(i)+LN(h), LSTM gates, LN(c), outputs -----
__global__ __launch_bounds__(256) void fuse_ln_lstm(
    const unsigned short* __restrict__ Gi, const unsigned short* __restrict__ Gh,
    const float* __restrict__ cx,
    const float* __restrict__ gi_g, const float* __restrict__ gi_b,
    const float* __restrict__ gh_g, const float* __restrict__ gh_b,
    const float* __restrict__ gc_g, const float* __restrict__ gc_b,
    float* __restrict__ out) {
  const int H = 1024;
  const size_t BH = (size_t)8192 * 1024;
  const int b = blockIdx.x, t = threadIdx.x;
  const int wid = t >> 6, lane = t & 63;

  __shared__ __align__(16) unsigned short lgi[4096];
  __shared__ __align__(16) unsigned short lgh[4096];
  __shared__ float lred[32];

  const uint4* gi_row = reinterpret_cast<const uint4*>(Gi) + (size_t)b * 512;
  const uint4* gh_row = reinterpret_cast<const uint4*>(Gh) + (size_t)b * 512;

  float si = 0.f, qi = 0.f, sh = 0.f, qh = 0.f;
#pragma unroll
  for (int c = 0; c < 2; ++c) {
    uint4 v = gi_row[c * 256 + t];
    uint4 w = gh_row[c * 256 + t];
    *reinterpret_cast<uint4*>(&lgi[(c * 256 + t) * 8]) = v;
    *reinterpret_cast<uint4*>(&lgh[(c * 256 + t) * 8]) = w;
    unsigned int uv[4] = {v.x, v.y, v.z, v.w};
    unsigned int uw[4] = {w.x, w.y, w.z, w.w};
#pragma unroll
    for (int e = 0; e < 4; ++e) {
      float a0 = __builtin_bit_cast(float, uv[e] << 16);
      float a1 = __builtin_bit_cast(float, uv[e] & 0xffff0000u);
      si += a0 + a1; qi += a0 * a0 + a1 * a1;
      float b0 = __builtin_bit_cast(float, uw[e] << 16);
      float b1 = __builtin_bit_cast(float, uw[e] & 0xffff0000u);
      sh += b0 + b1; qh += b0 * b0 + b1 * b1;
    }
  }
#pragma unroll
  for (int s = 32; s; s >>= 1) {
    si += __shfl_xor(si, s); qi += __shfl_xor(qi, s);
    sh += __shfl_xor(sh, s); qh += __shfl_xor(qh, s);
  }
  if (lane == 0) { lred[wid] = si; lred[4 + wid] = qi; lred[8 + wid] = sh; lred[12 + wid] = qh; }
  __syncthreads();
  float Si = lred[0] + lred[1] + lred[2] + lred[3];
  float Qi = lred[4] + lred[5] + lred[6] + lred[7];
  float Sh = lred[8] + lred[9] + lred[10] + lred[11];
  float Qh = lred[12] + lred[13] + lred[14] + lred[15];
  const float inv4096 = 1.f / 4096.f;
  float mui = Si * inv4096;
  float rsi = rsqrtf(fmaxf(Qi * inv4096 - mui * mui, 0.f) + 1e-5f);
  float muh = Sh * inv4096;
  float rsh = rsqrtf(fmaxf(Qh * inv4096 - muh * muh, 0.f) + 1e-5f);

  float cv[4], ov[4];
  float sc = 0.f, qc = 0.f;
#pragma unroll
  for (int k = 0; k < 4; ++k) {
    int h = t + 256 * k;
    float g0 = bfu2f(lgi[h]),        h0 = bfu2f(lgh[h]);
    float g1 = bfu2f(lgi[h + 1024]), h1 = bfu2f(lgh[h + 1024]);
    float g2 = bfu2f(lgi[h + 2048]), h2 = bfu2f(lgh[h + 2048]);
    float g3 = bfu2f(lgi[h + 3072]), h3 = bfu2f(lgh[h + 3072]);
    float vi = (g0 - mui) * rsi * gi_g[h]        + gi_b[h]        + (h0 - muh) * rsh * gh_g[h]        + gh_b[h];
    float vf = (g1 - mui) * rsi * gi_g[h + 1024] + gi_b[h + 1024] + (h1 - muh) * rsh * gh_g[h + 1024] + gh_b[h + 1024];
    float vg = (g2 - mui) * rsi * gi_g[h + 2048] + gi_b[h + 2048] + (h2 - muh) * rsh * gh_g[h + 2048] + gh_b[h + 2048];
    float vo = (g3 - mui) * rsi * gi_g[h + 3072] + gi_b[h + 3072] + (h3 - muh) * rsh * gh_g[h + 3072] + gh_b[h + 3072];
    float ig = sigmoidf_(vi), fg = sigmoidf_(vf), gg = tanhf_(vg), og = sigmoidf_(vo);
    float c = fg * cx[(size_t)b * H + h] + ig * gg;
    cv[k] = c; ov[k] = og;
    sc += c; qc += c * c;
  }
#pragma unroll
  for (int s = 32; s; s >>= 1) { sc += __shfl_xor(sc, s); qc += __shfl_xor(qc, s); }
  if (lane == 0) { lred[16 + wid] = sc; lred[20 + wid] = qc; }
  __syncthreads();
  float Sc = lred[16] + lred[17] + lred[18] + lred[19];
  float Qc = lred[20] + lred[21] + lred[22] + lred[23];
  const float inv1024 = 1.f / 1024.f;
  float muc = Sc * inv1024;
  float rsc = rsqrtf(fmaxf(Qc * inv1024 - muc * muc, 0.f) + 1e-5f);
#pragma unroll
  for (int k = 0; k < 4; ++k) {
    int h = t + 256 * k;
    float cy = (cv[k] - muc) * rsc * gc_g[h] + gc_b[h];
    float hy = ov[k] * tanhf_(cy);
    size_t o0 = (size_t)b * H + h;
    out[o0] = hy;            // hy
    out[BH + o0] = hy;       // hy (tuple repeats it)
    out[2 * BH + o0] = cy;   // cy
  }
}

extern "C" void kernel_launch(void* const* d_in, const int* in_sizes, int n_in,
                              void* d_out, int out_size, void* d_ws, size_t ws_size,
                              hipStream_t stream) {
  const float* x    = (const float*)d_in[0];
  const float* hx   = (const float*)d_in[1];
  const float* cx   = (const float*)d_in[2];
  const float* Wih  = (const float*)d_in[3];
  const float* Whh  = (const float*)d_in[4];
  const float* gi_g = (const float*)d_in[5];
  const float* gi_b = (const float*)d_in[6];
  const float* gh_g = (const float*)d_in[7];
  const float* gh_b = (const float*)d_in[8];
  const float* gc_g = (const float*)d_in[9];
  const float* gc_b = (const float*)d_in[10];
  float* out = (float*)d_out;

  const size_t NB = (size_t)8192 * 1024;   // x / hx elements
  const size_t NW = (size_t)4096 * 1024;   // W elements
  const size_t NG = (size_t)8192 * 4096;   // gate-matrix elements

  unsigned short* ws  = (unsigned short*)d_ws;
  unsigned short* xb  = ws;        // bf16 x
  unsigned short* hxb = xb + NB;   // bf16 hx
  unsigned short* wib = hxb + NB;  // bf16 W_ih
  unsigned short* whb = wib + NW;  // bf16 W_hh
  unsigned short* Gi  = whb + NW;  // bf16 x@W_ih^T
  unsigned short* Gh  = Gi + NG;   // bf16 hx@W_hh^T
  // total ws use: (2*NB + 2*NW + 2*NG) * 2B = 184.5 MB

  cvt_bf16_all<<<12288, 256, 0, stream>>>(x, xb, hx, hxb, Wih, wib, Whh, whb);

  dim3 gg(4096 / 128, 8192 / 128, 2);
  gemm_dual<<<gg, 256, 0, stream>>>(xb, hxb, wib, whb, Gi, Gh);

  fuse_ln_lstm<<<8192, 256, 0, stream>>>(Gi, Gh, cx, gi_g, gi_b, gh_g, gh_b,
                                         gc_g, gc_b, out);
}

// Round 17
// 231.028 us; speedup vs baseline: 1.1332x; 1.1332x over previous
//
#include <hip/hip_runtime.h>

typedef __attribute__((ext_vector_type(8))) short short8_t;   // 8 bf16 (4 VGPRs)
typedef __attribute__((ext_vector_type(4))) float f32x4;      // 4 fp32

#define AS1 __attribute__((address_space(1)))
#define AS3 __attribute__((address_space(3)))

__device__ inline void gload_lds16(const void* g, void* l) {
  // async global->LDS, 16B per lane; LDS dest is wave-uniform base + lane*16
  __builtin_amdgcn_global_load_lds((AS1 void*)g, (AS3 void*)l, 16, 0, 0);
}

__device__ inline unsigned short f2bf(float f) {  // RNE f32->bf16
  unsigned int u = __builtin_bit_cast(unsigned int, f);
  u += 0x7fffu + ((u >> 16) & 1u);
  return (unsigned short)(u >> 16);
}
__device__ inline float bfu2f(unsigned short u) {
  return __builtin_bit_cast(float, ((unsigned int)u) << 16);
}
__device__ inline float sigmoidf_(float x) {
  x = fminf(fmaxf(x, -30.f), 30.f);
  return 1.f / (1.f + __expf(-x));
}
__device__ inline float tanhf_(float x) {
  x = fminf(fmaxf(x, -15.f), 15.f);
  float e = __expf(2.f * x);
  return (e - 1.f) / (e + 1.f);
}

// ---------------- pass 0: f32 -> bf16 conversion (all 4 arrays, 1 launch) ---
__global__ __launch_bounds__(256) void cvt_bf16_all(
    const float* __restrict__ x,  unsigned short* __restrict__ xb,
    const float* __restrict__ hx, unsigned short* __restrict__ hxb,
    const float* __restrict__ Wi, unsigned short* __restrict__ wib,
    const float* __restrict__ Wh, unsigned short* __restrict__ whb) {
  int blk = blockIdx.x;
  const float* src; unsigned short* dst;
  if (blk < 4096)       { src = x;  dst = xb; }
  else if (blk < 8192)  { src = hx; dst = hxb; blk -= 4096; }
  else if (blk < 10240) { src = Wi; dst = wib; blk -= 8192; }
  else                  { src = Wh; dst = whb; blk -= 10240; }
  int i = (blk * 256 + threadIdx.x) * 8;
  const float4* s = reinterpret_cast<const float4*>(src + i);
  float4 a = s[0], b = s[1];
  union { unsigned short us[8]; uint4 v; } o;
  o.us[0] = f2bf(a.x); o.us[1] = f2bf(a.y); o.us[2] = f2bf(a.z); o.us[3] = f2bf(a.w);
  o.us[4] = f2bf(b.x); o.us[5] = f2bf(b.y); o.us[6] = f2bf(b.z); o.us[7] = f2bf(b.w);
  *reinterpret_cast<uint4*>(dst + i) = o.v;
}

// ---------------- pass 1: dual GEMM — R10 winner (151.9 us, 908 TF) --------
// C[m,n] = sum_k A[m,k]*B[n,k]. M=8192, N=4096, K=1024.
// BM=BN=256, BK=64, 512 thr = 8 waves (2M x 4N), wave tile 128x64, acc[8][4].
// LDS: [2 dbuf][2 half][128][64] bf16 per matrix = 64KB each, 128KB total.
// Per K-tile, 4 phases with TWO block barriers (empirical optimum over
// 8-barrier lockstep / 1-barrier BK=32 rotation / merged 2-phase / unroll /
// 128²@3blocks-per-CU — all measured worse, rounds 5-16):
//  P0: read A-lo(8)+B-lo(4); stage kt+1.B.h0; lgkm0; 16 MFMA (lo x lo)
//  P1: read B-hi(4);         stage kt+1.B.h1; lgkm0; 16 MFMA (lo x hi)
//  P2: read A-hi(8);                          lgkm0; 16 MFMA (hi x lo)
//      MID-BARRIER (all tile-kt reads retired block-wide)
//  P3: stage kt+2.A.h0+h1;                           16 MFMA (hi x hi)
//      vmcnt(4); BOUNDARY BARRIER
// Hazards: B(kt+1) -> opposite parity, behind previous boundary barrier;
// A(kt+2) -> current parity, behind mid-barrier (every wave's P2 lgkm0
// retired its tile-kt reads); boundary vmcnt(4) leaves only kt+2.A's 4
// loads outstanding -> kt+1 resident for all waves past the barrier.
// Swizzle (PMC-verified 0-conflict): 16B slot s of a 64-col row stored at
// phys slot s^(row&7); gload source pre-swizzled (rule #21); reads same XOR.
__global__ __launch_bounds__(512, 2) void gemm_dual(
    const unsigned short* __restrict__ Xb, const unsigned short* __restrict__ Hxb,
    const unsigned short* __restrict__ Wib, const unsigned short* __restrict__ Whb,
    unsigned short* __restrict__ Gi, unsigned short* __restrict__ Gh) {
  const int K = 1024, N = 4096, NT = 16;  // NT = K/64 K-tiles
  const unsigned short* A  = blockIdx.z ? Hxb : Xb;
  const unsigned short* Bw = blockIdx.z ? Whb : Wib;
  unsigned short* C        = blockIdx.z ? Gh : Gi;

  __shared__ __align__(16) unsigned short lA[2 * 2 * 128 * 64];  // 64 KB
  __shared__ __align__(16) unsigned short lB[2 * 2 * 128 * 64];  // 64 KB

  const int t    = threadIdx.x;        // 0..511
  const int wid  = t >> 6;
  const int lane = t & 63;
  const int fr = lane & 15, fq = lane >> 4;
  const int wm = wid >> 2;             // 0..1  (M-split)
  const int wn = wid & 3;              // 0..3  (N-split)
  const int m0 = blockIdx.y * 256, n0 = blockIdx.x * 256;

  // stage half-tile: X=0 -> A, X=1 -> B; h = row-half (0:rows 0-127, 1:128-255)
  auto stage = [&](int kt, int X, int h) {
    if (kt >= NT) return;
    const unsigned short* G = X ? Bw : A;
    const int r0 = (X ? n0 : m0) + h * 128;
    unsigned short* L = (X ? lB : lA) + (kt & 1) * 16384 + h * 8192;
#pragma unroll
    for (int g = 0; g < 2; ++g) {
      int idx = g * 512 + t;
      int row = idx >> 3;
      int ls  = (idx & 7) ^ (row & 7);
      gload_lds16(G + (size_t)(r0 + row) * K + kt * 64 + ls * 8,
                  L + g * 4096 + wid * 512);
    }
  };

  f32x4 acc[8][4];
#pragma unroll
  for (int i = 0; i < 8; ++i)
#pragma unroll
    for (int j = 0; j < 4; ++j) acc[i][j] = (f32x4){0.f, 0.f, 0.f, 0.f};

  // prologue: tile0 fully + tile1 A-halves in flight; wait tile0 (4 outstanding)
  stage(0, 0, 0); stage(0, 0, 1); stage(0, 1, 0); stage(0, 1, 1);
  stage(1, 0, 0); stage(1, 0, 1);
  asm volatile("s_waitcnt vmcnt(4)");
  __builtin_amdgcn_s_barrier();

  // read-side swizzle offsets (elements) for ks=0,1
  const int sw0 = ((fq)     ^ (fr & 7)) * 8;
  const int sw1 = ((fq + 4) ^ (fr & 7)) * 8;
  const int bro = (wn & 1) * 64;       // B row-in-half base

  short8_t av[4][2], bv[4][2];

  for (int kt = 0; kt < NT; ++kt) {
    const unsigned short* As = lA + (kt & 1) * 16384 + wm * 8192;
    const unsigned short* Bs = lB + (kt & 1) * 16384 + (wn >> 1) * 8192;

    // ---- P0: read A-lo + B-lo; stage (kt+1, B, half0); MFMA lo x lo ----
#pragma unroll
    for (int m = 0; m < 4; ++m) {
      av[m][0] = *reinterpret_cast<const short8_t*>(As + (m * 16 + fr) * 64 + sw0);
      av[m][1] = *reinterpret_cast<const short8_t*>(As + (m * 16 + fr) * 64 + sw1);
    }
#pragma unroll
    for (int n = 0; n < 2; ++n) {
      bv[n][0] = *reinterpret_cast<const short8_t*>(Bs + (bro + n * 16 + fr) * 64 + sw0);
      bv[n][1] = *reinterpret_cast<const short8_t*>(Bs + (bro + n * 16 + fr) * 64 + sw1);
    }
    stage(kt + 1, 1, 0);
    asm volatile("s_waitcnt lgkmcnt(0)");
    __builtin_amdgcn_s_setprio(1);
#pragma unroll
    for (int m = 0; m < 4; ++m)
#pragma unroll
      for (int n = 0; n < 2; ++n)
#pragma unroll
        for (int ks = 0; ks < 2; ++ks)
          acc[m][n] = __builtin_amdgcn_mfma_f32_16x16x32_bf16(av[m][ks], bv[n][ks], acc[m][n], 0, 0, 0);
    __builtin_amdgcn_s_setprio(0);

    // ---- P1: read B-hi; stage (kt+1, B, half1); MFMA lo x hi ----
#pragma unroll
    for (int n = 2; n < 4; ++n) {
      bv[n][0] = *reinterpret_cast<const short8_t*>(Bs + (bro + n * 16 + fr) * 64 + sw0);
      bv[n][1] = *reinterpret_cast<const short8_t*>(Bs + (bro + n * 16 + fr) * 64 + sw1);
    }
    stage(kt + 1, 1, 1);
    asm volatile("s_waitcnt lgkmcnt(0)");
    __builtin_amdgcn_s_setprio(1);
#pragma unroll
    for (int m = 0; m < 4; ++m)
#pragma unroll
      for (int n = 2; n < 4; ++n)
#pragma unroll
        for (int ks = 0; ks < 2; ++ks)
          acc[m][n] = __builtin_amdgcn_mfma_f32_16x16x32_bf16(av[m][ks], bv[n][ks], acc[m][n], 0, 0, 0);
    __builtin_amdgcn_s_setprio(0);

    // ---- P2: read A-hi (overwrites av); MFMA hi x lo; MID BARRIER ----
#pragma unroll
    for (int m = 0; m < 4; ++m) {
      av[m][0] = *reinterpret_cast<const short8_t*>(As + ((m + 4) * 16 + fr) * 64 + sw0);
      av[m][1] = *reinterpret_cast<const short8_t*>(As + ((m + 4) * 16 + fr) * 64 + sw1);
    }
    asm volatile("s_waitcnt lgkmcnt(0)");
    __builtin_amdgcn_s_setprio(1);
#pragma unroll
    for (int m = 0; m < 4; ++m)
#pragma unroll
      for (int n = 0; n < 2; ++n)
#pragma unroll
        for (int ks = 0; ks < 2; ++ks)
          acc[m + 4][n] = __builtin_amdgcn_mfma_f32_16x16x32_bf16(av[m][ks], bv[n][ks], acc[m + 4][n], 0, 0, 0);
    __builtin_amdgcn_s_setprio(0);
    // mid barrier: every wave's lgkm0 above retired all its tile-kt reads;
    // after this, staging kt+2.A (same parity) cannot race any read.
    __builtin_amdgcn_s_barrier();

    // ---- P3: stage (kt+2, A, both halves); MFMA hi x hi; boundary ----
    stage(kt + 2, 0, 0);
    stage(kt + 2, 0, 1);
    __builtin_amdgcn_s_setprio(1);
#pragma unroll
    for (int m = 0; m < 4; ++m)
#pragma unroll
      for (int n = 2; n < 4; ++n)
#pragma unroll
        for (int ks = 0; ks < 2; ++ks)
          acc[m + 4][n] = __builtin_amdgcn_mfma_f32_16x16x32_bf16(av[m][ks], bv[n][ks], acc[m + 4][n], 0, 0, 0);
    __builtin_amdgcn_s_setprio(0);
    // boundary: tile kt+1 fully resident past this barrier; only kt+2's A
    // halves (4 loads) may remain outstanding.
    if (kt + 2 < NT) {
      asm volatile("s_waitcnt vmcnt(4)");
    } else if (kt + 1 < NT) {
      asm volatile("s_waitcnt vmcnt(0)");
    }
    __builtin_amdgcn_s_barrier();
  }

  // epilogue: D row = fq*4 + r, col = fr (m89-verified layout)
#pragma unroll
  for (int m = 0; m < 8; ++m)
#pragma unroll
    for (int n = 0; n < 4; ++n)
#pragma unroll
      for (int r = 0; r < 4; ++r) {
        int row = m0 + wm * 128 + m * 16 + fq * 4 + r;
        int col = n0 + wn * 64 + n * 16 + fr;
        C[(size_t)row * N + col] = f2bf(acc[m][n][r]);
      }
}

// ---------------- pass 2: fused LN(i)+LN(h), LSTM gates, LN(c), outputs -----
__global__ __launch_bounds__(256) void fuse_ln_lstm(
    const unsigned short* __restrict__ Gi, const unsigned short* __restrict__ Gh,
    const float* __restrict__ cx,
    const float* __restrict__ gi_g, const float* __restrict__ gi_b,
    const float* __restrict__ gh_g, const float* __restrict__ gh_b,
    const float* __restrict__ gc_g, const float* __restrict__ gc_b,
    float* __restrict__ out) {
  const int H = 1024;
  const size_t BH = (size_t)8192 * 1024;
  const int b = blockIdx.x, t = threadIdx.x;
  const int wid = t >> 6, lane = t & 63;

  __shared__ __align__(16) unsigned short lgi[4096];
  __shared__ __align__(16) unsigned short lgh[4096];
  __shared__ float lred[32];

  const uint4* gi_row = reinterpret_cast<const uint4*>(Gi) + (size_t)b * 512;
  const uint4* gh_row = reinterpret_cast<const uint4*>(Gh) + (size_t)b * 512;

  float si = 0.f, qi = 0.f, sh = 0.f, qh = 0.f;
#pragma unroll
  for (int c = 0; c < 2; ++c) {
    uint4 v = gi_row[c * 256 + t];
    uint4 w = gh_row[c * 256 + t];
    *reinterpret_cast<uint4*>(&lgi[(c * 256 + t) * 8]) = v;
    *reinterpret_cast<uint4*>(&lgh[(c * 256 + t) * 8]) = w;
    unsigned int uv[4] = {v.x, v.y, v.z, v.w};
    unsigned int uw[4] = {w.x, w.y, w.z, w.w};
#pragma unroll
    for (int e = 0; e < 4; ++e) {
      float a0 = __builtin_bit_cast(float, uv[e] << 16);
      float a1 = __builtin_bit_cast(float, uv[e] & 0xffff0000u);
      si += a0 + a1; qi += a0 * a0 + a1 * a1;
      float b0 = __builtin_bit_cast(float, uw[e] << 16);
      float b1 = __builtin_bit_cast(float, uw[e] & 0xffff0000u);
      sh += b0 + b1; qh += b0 * b0 + b1 * b1;
    }
  }
#pragma unroll
  for (int s = 32; s; s >>= 1) {
    si += __shfl_xor(si, s); qi += __shfl_xor(qi, s);
    sh += __shfl_xor(sh, s); qh += __shfl_xor(qh, s);
  }
  if (lane == 0) { lred[wid] = si; lred[4 + wid] = qi; lred[8 + wid] = sh; lred[12 + wid] = qh; }
  __syncthreads();
  float Si = lred[0] + lred[1] + lred[2] + lred[3];
  float Qi = lred[4] + lred[5] + lred[6] + lred[7];
  float Sh = lred[8] + lred[9] + lred[10] + lred[11];
  float Qh = lred[12] + lred[13] + lred[14] + lred[15];
  const float inv4096 = 1.f / 4096.f;
  float mui = Si * inv4096;
  float rsi = rsqrtf(fmaxf(Qi * inv4096 - mui * mui, 0.f) + 1e-5f);
  float muh = Sh * inv4096;
  float rsh = rsqrtf(fmaxf(Qh * inv4096 - muh * muh, 0.f) + 1e-5f);

  float cv[4], ov[4];
  float sc = 0.f, qc = 0.f;
#pragma unroll
  for (int k = 0; k < 4; ++k) {
    int h = t + 256 * k;
    float g0 = bfu2f(lgi[h]),        h0 = bfu2f(lgh[h]);
    float g1 = bfu2f(lgi[h + 1024]), h1 = bfu2f(lgh[h + 1024]);
    float g2 = bfu2f(lgi[h + 2048]), h2 = bfu2f(lgh[h + 2048]);
    float g3 = bfu2f(lgi[h + 3072]), h3 = bfu2f(lgh[h + 3072]);
    float vi = (g0 - mui) * rsi * gi_g[h]        + gi_b[h]        + (h0 - muh) * rsh * gh_g[h]        + gh_b[h];
    float vf = (g1 - mui) * rsi * gi_g[h + 1024] + gi_b[h + 1024] + (h1 - muh) * rsh * gh_g[h + 1024] + gh_b[h + 1024];
    float vg = (g2 - mui) * rsi * gi_g[h + 2048] + gi_b[h + 2048] + (h2 - muh) * rsh * gh_g[h + 2048] + gh_b[h + 2048];
    float vo = (g3 - mui) * rsi * gi_g[h + 3072] + gi_b[h + 3072] + (h3 - muh) * rsh * gh_g[h + 3072] + gh_b[h + 3072];
    float ig = sigmoidf_(vi), fg = sigmoidf_(vf), gg = tanhf_(vg), og = sigmoidf_(vo);
    float c = fg * cx[(size_t)b * H + h] + ig * gg;
    cv[k] = c; ov[k] = og;
    sc += c; qc += c * c;
  }
#pragma unroll
  for (int s = 32; s; s >>= 1) { sc += __shfl_xor(sc, s); qc += __shfl_xor(qc, s); }
  if (lane == 0) { lred[16 + wid] = sc; lred[20 + wid] = qc; }
  __syncthreads();
  float Sc = lred[16] + lred[17] + lred[18] + lred[19];
  float Qc = lred[20] + lred[21] + lred[22] + lred[23];
  const float inv1024 = 1.f / 1024.f;
  float muc = Sc * inv1024;
  float rsc = rsqrtf(fmaxf(Qc * inv1024 - muc * muc, 0.f) + 1e-5f);
#pragma unroll
  for (int k = 0; k < 4; ++k) {
    int h = t + 256 * k;
    float cy = (cv[k] - muc) * rsc * gc_g[h] + gc_b[h];
    float hy = ov[k] * tanhf_(cy);
    size_t o0 = (size_t)b * H + h;
    out[o0] = hy;            // hy
    out[BH + o0] = hy;       // hy (tuple repeats it)
    out[2 * BH + o0] = cy;   // cy
  }
}

extern "C" void kernel_launch(void* const* d_in, const int* in_sizes, int n_in,
                              void* d_out, int out_size, void* d_ws, size_t ws_size,
                              hipStream_t stream) {
  const float* x    = (const float*)d_in[0];
  const float* hx   = (const float*)d_in[1];
  const float* cx   = (const float*)d_in[2];
  const float* Wih  = (const float*)d_in[3];
  const float* Whh  = (const float*)d_in[4];
  const float* gi_g = (const float*)d_in[5];
  const float* gi_b = (const float*)d_in[6];
  const float* gh_g = (const float*)d_in[7];
  const float* gh_b = (const float*)d_in[8];
  const float* gc_g = (const float*)d_in[9];
  const float* gc_b = (const float*)d_in[10];
  float* out = (float*)d_out;

  const size_t NB = (size_t)8192 * 1024;   // x / hx elements
  const size_t NW = (size_t)4096 * 1024;   // W elements
  const size_t NG = (size_t)8192 * 4096;   // gate-matrix elements

  unsigned short* ws  = (unsigned short*)d_ws;
  unsigned short* xb  = ws;        // bf16 x
  unsigned short* hxb = xb + NB;   // bf16 hx
  unsigned short* wib = hxb + NB;  // bf16 W_ih
  unsigned short* whb = wib + NW;  // bf16 W_hh
  unsigned short* Gi  = whb + NW;  // bf16 x@W_ih^T
  unsigned short* Gh  = Gi + NG;   // bf16 hx@W_hh^T
  // total ws use: (2*NB + 2*NW + 2*NG) * 2B = 184.5 MB

  cvt_bf16_all<<<12288, 256, 0, stream>>>(x, xb, hx, hxb, Wih, wib, Whh, whb);

  dim3 gg(4096 / 256, 8192 / 256, 2);
  gemm_dual<<<gg, 512, 0, stream>>>(xb, hxb, wib, whb, Gi, Gh);

  fuse_ln_lstm<<<8192, 256, 0, stream>>>(Gi, Gh, cx, gi_g, gi_b, gh_g, gh_b,
                                         gc_g, gc_b, out);
}